// Round 12
// baseline (57.507 us; speedup 1.0000x reference)
//
#include <hip/hip_runtime.h>
#include <cstddef>
#include <cstdint>

typedef __attribute__((ext_vector_type(8))) short bf16x8;
typedef __attribute__((ext_vector_type(4))) unsigned short ushort4v;
typedef __attribute__((ext_vector_type(8))) unsigned short ushort8v;
typedef __attribute__((ext_vector_type(16))) float f32x16;

__device__ __forceinline__ unsigned short f2bf(float f) {
  union { float f; unsigned u; } v; v.f = f;
  unsigned r = v.u + 0x7FFFu + ((v.u >> 16) & 1u);  // round-to-nearest-even
  return (unsigned short)(r >> 16);
}

// async global->LDS, 16B per lane; dest = wave-uniform base + lane*16
__device__ __forceinline__ void gload16(const void* g, void* l) {
  __builtin_amdgcn_global_load_lds(
      (const __attribute__((address_space(1))) void*)(unsigned long long)(uintptr_t)g,
      (__attribute__((address_space(3))) void*)(unsigned)(uintptr_t)l, 16, 0, 0);
}

// ---------------- stage 1: x -> bf16 channel-last (zero-padded) + gap partials
// grid = 4096 blocks ((b,g,row-pair)), 256 threads.
// xt layout: [b][g][66 row][66 col][32 ic] bf16, 1-px zero halo.
#define PADC 132
__global__ __launch_bounds__(256) void prep_kernel(
    const float* __restrict__ x, unsigned short* __restrict__ xt,
    float* __restrict__ partials) {
  __shared__ unsigned short cm[32 * PADC];  // channel-major bf16: [ic][128 px]
  __shared__ float sred[32][32];
  const int bid = blockIdx.x;
  // XCD-chunked: xt[bg] written on XCD bg>>4 (matches conv reader)
  const int wkr = ((bid & 7) << 9) | (bid >> 3);
  const int yp = wkr & 31, g = (wkr >> 5) & 7, b = wkr >> 8;
  const int y0 = yp * 2;
  const int tid = threadIdx.x;
  const float* xg = x + (size_t)(b * 256 + g * 32) * 4096;

  float csum[4];
#pragma unroll
  for (int j = 0; j < 4; ++j) {
    const int idx = tid + 256 * j;
    const int ic = idx >> 5;  // 0..31
    const int r = idx & 31;
    const int ry = r >> 4, gx4 = (r & 15) * 4;
    const float4 v = *reinterpret_cast<const float4*>(
        xg + (size_t)ic * 4096 + (y0 + ry) * 64 + gx4);
    csum[j] = v.x + v.y + v.z + v.w;
    ushort4v s;
    s[0] = f2bf(v.x); s[1] = f2bf(v.y); s[2] = f2bf(v.z); s[3] = f2bf(v.w);
    *reinterpret_cast<ushort4v*>(&cm[ic * PADC + ry * 64 + gx4]) = s;
  }
#pragma unroll
  for (int j = 0; j < 4; ++j) {
    const int ic = (tid >> 5) + 8 * j;
    sred[ic][tid & 31] = csum[j];
  }
  __syncthreads();

  if (tid < 32) {
    float s = 0.f;
#pragma unroll
    for (int i = 0; i < 32; ++i) s += sred[tid][i];
    partials[(size_t)(b * 256 + g * 32 + tid) * 32 + yp] = s;
  }

  const size_t xtb = (size_t)(b * 8 + g) * (66 * 66 * 32);
#pragma unroll
  for (int jj = 0; jj < 2; ++jj) {
    const int o = tid + 256 * jj;  // 0..511
    const int px = o >> 2, icq = o & 3;
    const int ry = px >> 6, gx = px & 63;
    ushort8v t;
#pragma unroll
    for (int c2 = 0; c2 < 8; ++c2) t[c2] = cm[(icq * 8 + c2) * PADC + px];
    *reinterpret_cast<ushort8v*>(
        &xt[xtb + ((size_t)(y0 + ry + 1) * 66 + (gx + 1)) * 32 + icq * 8]) = t;
  }

  const ushort8v z = {0, 0, 0, 0, 0, 0, 0, 0};
  if (tid < 16) {
    const int rr = tid >> 3;
    const int side = (tid >> 2) & 1;
    const int icq = tid & 3;
    const int col = side * 65;
    *reinterpret_cast<ushort8v*>(
        &xt[xtb + ((size_t)(y0 + rr + 1) * 66 + col) * 32 + icq * 8]) = z;
  }
  if (yp == 0 || yp == 31) {
    const int row = (yp == 0) ? 0 : 65;
    for (int o = tid; o < 66 * 4; o += 256) {
      const int col = o >> 2, icq = o & 3;
      *reinterpret_cast<ushort8v*>(
          &xt[xtb + ((size_t)row * 66 + col) * 32 + icq * 8]) = z;
    }
  }
}

// ---------------- stage 2: glgf generation, gate FOLDED into weights ----
// grid = 128 blocks, 256 threads. wpack[bg] holds (w * c) in A-frag order.
__global__ __launch_bounds__(256) void glgf_pack(
    const float* __restrict__ partials,
    const float* __restrict__ w1l, const float* __restrict__ w1g1,
    const float* __restrict__ w1g2, const float* __restrict__ w2l,
    const float* __restrict__ w2g,
    const float* __restrict__ v1l, const float* __restrict__ v1g1,
    const float* __restrict__ v1g2, const float* __restrict__ v2l,
    const float* __restrict__ v2g,
    unsigned short* __restrict__ wpack) {
  __shared__ float gapL[256];
  __shared__ float t1L[16];
  __shared__ float h1L[256];
  __shared__ float red[256];
  __shared__ float cLs[32];
  const int bid = blockIdx.x;
  const int bg = ((bid & 7) << 4) | (bid >> 3);  // block on XCD bg>>4
  const int g = bg & 7, b = bg >> 3;
  const int c = threadIdx.x;
  {
    float s = 0.f;
    const float* pp = partials + (size_t)(b * 256 + c) * 32;
#pragma unroll
    for (int i = 0; i < 32; ++i) s += pp[i];
    gapL[c] = s * (1.f / 4096.f);
  }
  __syncthreads();

  const int gbase = c & ~15;
  // ---- generator 1 ----
  float local1 = 0.f;
#pragma unroll
  for (int i = 0; i < 16; ++i) local1 += gapL[gbase + i] * w1l[c * 16 + i];
  if (c < 16) {
    float t = 0.f;
#pragma unroll
    for (int i = 0; i < 16; ++i) t += gapL[c * 16 + i] * w1g1[c * 16 + i];
    t1L[c] = t;
  }
  __syncthreads();
  float glob1 = 0.f;
#pragma unroll
  for (int gg = 0; gg < 16; ++gg) glob1 += t1L[gg] * w1g2[c * 16 + gg];
  const float h1 = 1.f / (1.f + expf(-(local1 + glob1)));
  h1L[c] = h1;
  red[c] = h1 * w2g[c];
  __syncthreads();
  for (int s = 128; s > 0; s >>= 1) {
    if (c < s) red[c] += red[c + s];
    __syncthreads();
  }
  const float glob2 = red[0];

  // ---- generator 2 (gate), folded into pack ----
  float local2 = 0.f;
#pragma unroll
  for (int i = 0; i < 16; ++i) local2 += gapL[gbase + i] * v1l[c * 16 + i];
  if (c < 16) {
    float t = 0.f;
#pragma unroll
    for (int i = 0; i < 16; ++i) t += gapL[c * 16 + i] * v1g1[c * 16 + i];
    t1L[c] = t;
  }
  __syncthreads();  // also separates red[0] reads from red reuse
  float glob1b = 0.f;
#pragma unroll
  for (int gg = 0; gg < 16; ++gg) glob1b += t1L[gg] * v1g2[c * 16 + gg];
  const float h2 = 1.f / (1.f + expf(-(local2 + glob1b)));
  red[c] = h2 * v2g[c];
  __syncthreads();
  for (int s = 128; s > 0; s >>= 1) {
    if (c < s) red[c] += red[c + s];
    __syncthreads();
  }
  if (c < 32) {
    const int o = g * 32 + c;
    float l = 0.f;
#pragma unroll
    for (int i = 0; i < 16; ++i) l += gapL[(o & ~15) + i] * v1l[o * 16 + i];
    float gl = 0.f;
#pragma unroll
    for (int gg = 0; gg < 16; ++gg) gl += t1L[gg] * v1g2[o * 16 + gg];
    const float h2o = 1.f / (1.f + expf(-(l + gl)));
    cLs[c] = h2o * v2l[o] + red[0];
  }
  __syncthreads();

  // ---- pack (w * c) for this (b,g): A-fragment order ----
  unsigned short* wpo = wpack + (size_t)bg * 9216;
#pragma unroll 4
  for (int it = 0; it < 36; ++it) {
    const int idx = it * 256 + c;
    const int kk = idx >> 9;
    const int rem = idx & 511;
    const int l = rem >> 3, e = rem & 7;
    const int oc = l & 31, hi = l >> 5;
    const int ic = ((kk & 1) << 4) + hi * 8 + e;
    const int sp = kk >> 1;
    const int o = (g << 5) + oc;
    const float wv = h1L[o] * w2l[o * 288 + ic * 9 + sp] + glob2;
    wpo[idx] = f2bf(wv * cLs[oc]);
  }
}

// ---------------- stage 3: conv — wave-owns-a-row, 1.0 LDS reads/MFMA ----
// grid = 2048 blocks ((b,g) x 4-row strip), 256 threads = 4 waves, 3 blk/CU.
// A in VGPR (from L2-hot wpack); 6 xt rows staged once; ONE barrier;
// each wave: row y0+wave, both px halves (acc0/acc1); deferred stores.
__global__ __launch_bounds__(256, 3) void conv_kernel(
    const unsigned short* __restrict__ wpack,
    const unsigned short* __restrict__ xt, float* __restrict__ out) {
  __shared__ __align__(16) unsigned short btile[12672];  // 6r x 4cq x 66px x 16B

  const int bid = blockIdx.x;
  const int wkr = ((bid & 7) << 8) | (bid >> 3);  // XCD-chunked, bijective
  const int yb = wkr & 15;             // strip: output rows yb*4 .. +3
  const int bg = wkr >> 4;             // bg>>4 == XCD id (matches prep/glgf)
  const int g = bg & 7, b = bg >> 3;
  const int tid = threadIdx.x;
  const int lane = tid & 63, wave = tid >> 6;
  const int n = lane & 31, hi = lane >> 5;

  const char* xbase = (const char*)xt + (size_t)bg * 278784;  // 66*66*32*2 B
  const int y0 = yb * 4;  // xt rows y0 .. y0+5 (output rows y0..y0+3)

  // ---- A fragments -> VGPR (gate pre-folded); 18 x b128 from L2 ----
  const unsigned short* wp = wpack + (size_t)bg * 9216 + lane * 8;
  bf16x8 a[18];
#pragma unroll
  for (int kk = 0; kk < 18; ++kk) {
    a[kk] = *reinterpret_cast<const bf16x8*>(wp + kk * 512);
    asm volatile("" : "+v"(a[kk]));  // keep in VGPRs ((256,3): cap 170)
  }

  // ---- stage 6-row strip: linear LDS dest, inverse-swizzled source ----
#pragma unroll
  for (int i = 0; i < 7; ++i) {
    const int li = i * 256 + tid;  // chunk index, 1584 chunks of 16B
    if (li < 1584) {
      const int r = li / 264, rem = li - r * 264;
      const int cqs = rem / 66, px = rem % 66;
      const int cq = cqs ^ (px & 3);
      gload16(xbase + (y0 + r) * 4224 + px * 64 + cq * 16,
              (char*)btile + i * 4096 + wave * 1024);
    }
  }
  asm volatile("s_waitcnt vmcnt(0) lgkmcnt(0)\n\ts_barrier" ::: "memory");
  __builtin_amdgcn_sched_barrier(0);

  // ---- 36 MFMA: row y0+wave, both halves; A shared, 2 B-reads per kk ----
  f32x16 acc0, acc1;
#pragma unroll
  for (int i = 0; i < 16; ++i) { acc0[i] = 0.f; acc1[i] = 0.f; }

  __builtin_amdgcn_s_setprio(1);
#pragma unroll
  for (int kk = 0; kk < 18; ++kk) {
    const int sp = kk >> 1;
    const int ky = sp / 3, kx = sp % 3;
    const int cq = ((kk & 1) << 1) + hi;
    const int pxA = n + kx;
    const int pxB = 32 + n + kx;
    const bf16x8 bf0 = *reinterpret_cast<const bf16x8*>(
        &btile[((((wave + ky) << 2) + (cq ^ (pxA & 3))) * 66 + pxA) * 8]);
    const bf16x8 bf1 = *reinterpret_cast<const bf16x8*>(
        &btile[((((wave + ky) << 2) + (cq ^ (pxB & 3))) * 66 + pxB) * 8]);
    acc0 = __builtin_amdgcn_mfma_f32_32x32x16_bf16(a[kk], bf0, acc0, 0, 0, 0);
    acc1 = __builtin_amdgcn_mfma_f32_32x32x16_bf16(a[kk], bf1, acc1, 0, 0, 0);
  }
  __builtin_amdgcn_s_setprio(0);

  // ---- epilogue: deferred fire-and-forget stores (gate folded in wpack) ----
  const int y = y0 + wave;
  float* ob = out + (size_t)(b * 256 + g * 32) * 4096 + y * 64 + n +
              (size_t)(hi << 2) * 4096;
#pragma unroll
  for (int r = 0; r < 16; ++r) {
    const int row = (r & 3) + ((r >> 2) << 3);  // hi-term folded into ob
    ob[(size_t)row * 4096] = acc0[r];
    ob[(size_t)row * 4096 + 32] = acc1[r];
  }
}

extern "C" void kernel_launch(void* const* d_in, const int* in_sizes, int n_in,
                              void* d_out, int out_size, void* d_ws,
                              size_t ws_size, hipStream_t stream) {
  const float* x    = (const float*)d_in[0];
  const float* w1l  = (const float*)d_in[1];
  const float* w1g1 = (const float*)d_in[2];
  const float* w1g2 = (const float*)d_in[3];
  const float* w2l  = (const float*)d_in[4];
  const float* w2g  = (const float*)d_in[5];
  const float* v1l  = (const float*)d_in[6];
  const float* v1g1 = (const float*)d_in[7];
  const float* v1g2 = (const float*)d_in[8];
  const float* v2l  = (const float*)d_in[9];
  const float* v2g  = (const float*)d_in[10];
  float* out = (float*)d_out;

  unsigned short* xt = (unsigned short*)d_ws;      // 17,842,176 bf16
  float* partials = (float*)(xt + 17842176);       // 131,072 f32
  unsigned short* wpack = (unsigned short*)(partials + 131072);  // 1,179,648 bf16

  prep_kernel<<<4096, 256, 0, stream>>>(x, xt, partials);
  glgf_pack<<<128, 256, 0, stream>>>(partials, w1l, w1g1, w1g2, w2l, w2g,
                                     v1l, v1g1, v1g2, v2l, v2g, wpack);
  conv_kernel<<<2048, 256, 0, stream>>>(wpack, xt, out);
}

// Round 13
// 52.576 us; speedup vs baseline: 1.0938x; 1.0938x over previous
//
#include <hip/hip_runtime.h>
#include <cstddef>
#include <cstdint>

typedef __attribute__((ext_vector_type(8))) short bf16x8;
typedef __attribute__((ext_vector_type(4))) unsigned short ushort4v;
typedef __attribute__((ext_vector_type(8))) unsigned short ushort8v;
typedef __attribute__((ext_vector_type(16))) float f32x16;

__device__ __forceinline__ unsigned short f2bf(float f) {
  union { float f; unsigned u; } v; v.f = f;
  unsigned r = v.u + 0x7FFFu + ((v.u >> 16) & 1u);  // round-to-nearest-even
  return (unsigned short)(r >> 16);
}

// async global->LDS, 16B per lane; dest = wave-uniform base + lane*16
__device__ __forceinline__ void gload16(const void* g, void* l) {
  __builtin_amdgcn_global_load_lds(
      (const __attribute__((address_space(1))) void*)(unsigned long long)(uintptr_t)g,
      (__attribute__((address_space(3))) void*)(unsigned)(uintptr_t)l, 16, 0, 0);
}

// ---------------- stage 1: x -> bf16 channel-last (zero-padded) + gap partials
// grid = 4096 blocks ((b,g,row-pair)), 256 threads.
// xt layout: [b][g][66 row][66 col][32 ic] bf16, 1-px zero halo.
#define PADC 132
__global__ __launch_bounds__(256) void prep_kernel(
    const float* __restrict__ x, unsigned short* __restrict__ xt,
    float* __restrict__ partials) {
  __shared__ unsigned short cm[32 * PADC];  // channel-major bf16: [ic][128 px]
  __shared__ float sred[32][32];
  const int bid = blockIdx.x;
  // XCD-chunked: xt[bg] written on XCD bg>>4 (matches conv reader)
  const int wkr = ((bid & 7) << 9) | (bid >> 3);
  const int yp = wkr & 31, g = (wkr >> 5) & 7, b = wkr >> 8;
  const int y0 = yp * 2;
  const int tid = threadIdx.x;
  const float* xg = x + (size_t)(b * 256 + g * 32) * 4096;

  float csum[4];
#pragma unroll
  for (int j = 0; j < 4; ++j) {
    const int idx = tid + 256 * j;
    const int ic = idx >> 5;  // 0..31
    const int r = idx & 31;
    const int ry = r >> 4, gx4 = (r & 15) * 4;
    const float4 v = *reinterpret_cast<const float4*>(
        xg + (size_t)ic * 4096 + (y0 + ry) * 64 + gx4);
    csum[j] = v.x + v.y + v.z + v.w;
    ushort4v s;
    s[0] = f2bf(v.x); s[1] = f2bf(v.y); s[2] = f2bf(v.z); s[3] = f2bf(v.w);
    *reinterpret_cast<ushort4v*>(&cm[ic * PADC + ry * 64 + gx4]) = s;
  }
#pragma unroll
  for (int j = 0; j < 4; ++j) {
    const int ic = (tid >> 5) + 8 * j;
    sred[ic][tid & 31] = csum[j];
  }
  __syncthreads();

  if (tid < 32) {
    float s = 0.f;
#pragma unroll
    for (int i = 0; i < 32; ++i) s += sred[tid][i];
    partials[(size_t)(b * 256 + g * 32 + tid) * 32 + yp] = s;
  }

  const size_t xtb = (size_t)(b * 8 + g) * (66 * 66 * 32);
#pragma unroll
  for (int jj = 0; jj < 2; ++jj) {
    const int o = tid + 256 * jj;  // 0..511
    const int px = o >> 2, icq = o & 3;
    const int ry = px >> 6, gx = px & 63;
    ushort8v t;
#pragma unroll
    for (int c2 = 0; c2 < 8; ++c2) t[c2] = cm[(icq * 8 + c2) * PADC + px];
    *reinterpret_cast<ushort8v*>(
        &xt[xtb + ((size_t)(y0 + ry + 1) * 66 + (gx + 1)) * 32 + icq * 8]) = t;
  }

  const ushort8v z = {0, 0, 0, 0, 0, 0, 0, 0};
  if (tid < 16) {
    const int rr = tid >> 3;
    const int side = (tid >> 2) & 1;
    const int icq = tid & 3;
    const int col = side * 65;
    *reinterpret_cast<ushort8v*>(
        &xt[xtb + ((size_t)(y0 + rr + 1) * 66 + col) * 32 + icq * 8]) = z;
  }
  if (yp == 0 || yp == 31) {
    const int row = (yp == 0) ? 0 : 65;
    for (int o = tid; o < 66 * 4; o += 256) {
      const int col = o >> 2, icq = o & 3;
      *reinterpret_cast<ushort8v*>(
          &xt[xtb + ((size_t)row * 66 + col) * 32 + icq * 8]) = z;
    }
  }
}

// ---------------- stage 2: glgf generation, gate FOLDED into weights ----
// grid = 128 blocks, 256 threads. wpack[bg] holds (w * c) in A-frag order.
__global__ __launch_bounds__(256) void glgf_pack(
    const float* __restrict__ partials,
    const float* __restrict__ w1l, const float* __restrict__ w1g1,
    const float* __restrict__ w1g2, const float* __restrict__ w2l,
    const float* __restrict__ w2g,
    const float* __restrict__ v1l, const float* __restrict__ v1g1,
    const float* __restrict__ v1g2, const float* __restrict__ v2l,
    const float* __restrict__ v2g,
    unsigned short* __restrict__ wpack) {
  __shared__ float gapL[256];
  __shared__ float t1L[16];
  __shared__ float h1L[256];
  __shared__ float red[256];
  __shared__ float cLs[32];
  const int bid = blockIdx.x;
  const int bg = ((bid & 7) << 4) | (bid >> 3);  // block on XCD bg>>4
  const int g = bg & 7, b = bg >> 3;
  const int c = threadIdx.x;
  {
    float s = 0.f;
    const float* pp = partials + (size_t)(b * 256 + c) * 32;
#pragma unroll
    for (int i = 0; i < 32; ++i) s += pp[i];
    gapL[c] = s * (1.f / 4096.f);
  }
  __syncthreads();

  const int gbase = c & ~15;
  // ---- generator 1 ----
  float local1 = 0.f;
#pragma unroll
  for (int i = 0; i < 16; ++i) local1 += gapL[gbase + i] * w1l[c * 16 + i];
  if (c < 16) {
    float t = 0.f;
#pragma unroll
    for (int i = 0; i < 16; ++i) t += gapL[c * 16 + i] * w1g1[c * 16 + i];
    t1L[c] = t;
  }
  __syncthreads();
  float glob1 = 0.f;
#pragma unroll
  for (int gg = 0; gg < 16; ++gg) glob1 += t1L[gg] * w1g2[c * 16 + gg];
  const float h1 = 1.f / (1.f + expf(-(local1 + glob1)));
  h1L[c] = h1;
  red[c] = h1 * w2g[c];
  __syncthreads();
  for (int s = 128; s > 0; s >>= 1) {
    if (c < s) red[c] += red[c + s];
    __syncthreads();
  }
  const float glob2 = red[0];

  // ---- generator 2 (gate), folded into pack ----
  float local2 = 0.f;
#pragma unroll
  for (int i = 0; i < 16; ++i) local2 += gapL[gbase + i] * v1l[c * 16 + i];
  if (c < 16) {
    float t = 0.f;
#pragma unroll
    for (int i = 0; i < 16; ++i) t += gapL[c * 16 + i] * v1g1[c * 16 + i];
    t1L[c] = t;
  }
  __syncthreads();  // also separates red[0] reads from red reuse
  float glob1b = 0.f;
#pragma unroll
  for (int gg = 0; gg < 16; ++gg) glob1b += t1L[gg] * v1g2[c * 16 + gg];
  const float h2 = 1.f / (1.f + expf(-(local2 + glob1b)));
  red[c] = h2 * v2g[c];
  __syncthreads();
  for (int s = 128; s > 0; s >>= 1) {
    if (c < s) red[c] += red[c + s];
    __syncthreads();
  }
  if (c < 32) {
    const int o = g * 32 + c;
    float l = 0.f;
#pragma unroll
    for (int i = 0; i < 16; ++i) l += gapL[(o & ~15) + i] * v1l[o * 16 + i];
    float gl = 0.f;
#pragma unroll
    for (int gg = 0; gg < 16; ++gg) gl += t1L[gg] * v1g2[o * 16 + gg];
    const float h2o = 1.f / (1.f + expf(-(l + gl)));
    cLs[c] = h2o * v2l[o] + red[0];
  }
  __syncthreads();

  // ---- pack (w * c) for this (b,g): A-fragment order ----
  unsigned short* wpo = wpack + (size_t)bg * 9216;
#pragma unroll 4
  for (int it = 0; it < 36; ++it) {
    const int idx = it * 256 + c;
    const int kk = idx >> 9;
    const int rem = idx & 511;
    const int l = rem >> 3, e = rem & 7;
    const int oc = l & 31, hi = l >> 5;
    const int ic = ((kk & 1) << 4) + hi * 8 + e;
    const int sp = kk >> 1;
    const int o = (g << 5) + oc;
    const float wv = h1L[o] * w2l[o * 288 + ic * 9 + sp] + glob2;
    wpo[idx] = f2bf(wv * cLs[oc]);
  }
}

// ---------------- stage 3: conv — 512-thread blocks, 8-row strip staged once,
// ONE barrier, 16 waves/CU, wave = (row x both halves), deferred stores ----
// grid = 1024 blocks ((b,g) x 8-row strip), 2 blocks/CU.
__global__ __launch_bounds__(512, 4) void conv_kernel(
    const unsigned short* __restrict__ wpack,
    const unsigned short* __restrict__ xt, float* __restrict__ out) {
  __shared__ __align__(16) unsigned short wpl[9216];    // 18432 B (A frags)
  __shared__ __align__(16) unsigned short btile[21120]; // 42240 B (10 rows)

  const int bid = blockIdx.x;
  const int wkr = ((bid & 7) << 7) | (bid >> 3);  // XCD-chunked, bijective
  const int yq = wkr & 7;              // strip: output rows yq*8 .. +7
  const int bg = wkr >> 3;             // bg>>4 == XCD id (matches prep/glgf)
  const int g = bg & 7, b = bg >> 3;
  const int tid = threadIdx.x;
  const int lane = tid & 63, wave = tid >> 6;   // 8 waves
  const int n = lane & 31, hi = lane >> 5;

  const char* xbase = (const char*)xt + (size_t)bg * 278784;  // 66*66*32*2 B
  const int y0 = yq * 8;  // xt rows y0 .. y0+9 (output rows y0..y0+7)

  // ---- stage 10-row strip: linear LDS dest, inverse-swizzled source ----
#pragma unroll
  for (int i = 0; i < 6; ++i) {
    const int li = i * 512 + tid;  // chunk index, 2640 chunks of 16B
    if (li < 2640) {
      const int r = li / 264, rem = li - r * 264;
      const int cqs = rem / 66, px = rem % 66;
      const int cq = cqs ^ (px & 3);
      gload16(xbase + (y0 + r) * 4224 + px * 64 + cq * 16,
              (char*)btile + i * 8192 + wave * 1024);
    }
  }

  // ---- wpl copy: wpack (L2-hot) -> regs -> LDS ----
  {
    const uint4* src = reinterpret_cast<const uint4*>(wpack + (size_t)bg * 9216);
    uint4* dst = reinterpret_cast<uint4*>(wpl);
#pragma unroll
    for (int i = 0; i < 3; ++i) {
      const int li = i * 512 + tid;
      if (li < 1152) dst[li] = src[li];
    }
  }

  // single barrier: all staging (vmem + lds) complete
  asm volatile("s_waitcnt vmcnt(0) lgkmcnt(0)\n\ts_barrier" ::: "memory");
  __builtin_amdgcn_sched_barrier(0);

  // ---- 36 MFMA per wave: row y0+wave, both px halves ----
  f32x16 acc0, acc1;
#pragma unroll
  for (int i = 0; i < 16; ++i) { acc0[i] = 0.f; acc1[i] = 0.f; }

  __builtin_amdgcn_s_setprio(1);
#pragma unroll
  for (int kk = 0; kk < 18; ++kk) {
    const int sp = kk >> 1;
    const int ky = sp / 3, kx = sp % 3;
    const int cq = ((kk & 1) << 1) + hi;
    const int pxA = n + kx;
    const int pxB = 32 + n + kx;
    const bf16x8 af =
        *reinterpret_cast<const bf16x8*>(&wpl[kk * 512 + lane * 8]);
    const bf16x8 bf0 = *reinterpret_cast<const bf16x8*>(
        &btile[((((wave + ky) << 2) + (cq ^ (pxA & 3))) * 66 + pxA) * 8]);
    const bf16x8 bf1 = *reinterpret_cast<const bf16x8*>(
        &btile[((((wave + ky) << 2) + (cq ^ (pxB & 3))) * 66 + pxB) * 8]);
    acc0 = __builtin_amdgcn_mfma_f32_32x32x16_bf16(af, bf0, acc0, 0, 0, 0);
    acc1 = __builtin_amdgcn_mfma_f32_32x32x16_bf16(af, bf1, acc1, 0, 0, 0);
  }
  __builtin_amdgcn_s_setprio(0);

  // ---- epilogue: deferred fire-and-forget stores (gate folded in wpack) ----
  const int y = y0 + wave;
  float* ob = out + (size_t)(b * 256 + g * 32) * 4096 + y * 64 + n +
              (size_t)(hi << 2) * 4096;
#pragma unroll
  for (int r = 0; r < 16; ++r) {
    const int row = (r & 3) + ((r >> 2) << 3);  // hi-term folded into ob
    ob[(size_t)row * 4096] = acc0[r];
    ob[(size_t)row * 4096 + 32] = acc1[r];
  }
}

extern "C" void kernel_launch(void* const* d_in, const int* in_sizes, int n_in,
                              void* d_out, int out_size, void* d_ws,
                              size_t ws_size, hipStream_t stream) {
  const float* x    = (const float*)d_in[0];
  const float* w1l  = (const float*)d_in[1];
  const float* w1g1 = (const float*)d_in[2];
  const float* w1g2 = (const float*)d_in[3];
  const float* w2l  = (const float*)d_in[4];
  const float* w2g  = (const float*)d_in[5];
  const float* v1l  = (const float*)d_in[6];
  const float* v1g1 = (const float*)d_in[7];
  const float* v1g2 = (const float*)d_in[8];
  const float* v2l  = (const float*)d_in[9];
  const float* v2g  = (const float*)d_in[10];
  float* out = (float*)d_out;

  unsigned short* xt = (unsigned short*)d_ws;      // 17,842,176 bf16
  float* partials = (float*)(xt + 17842176);       // 131,072 f32
  unsigned short* wpack = (unsigned short*)(partials + 131072);  // 1,179,648 bf16

  prep_kernel<<<4096, 256, 0, stream>>>(x, xt, partials);
  glgf_pack<<<128, 256, 0, stream>>>(partials, w1l, w1g1, w1g2, w2l, w2g,
                                     v1l, v1g1, v1g2, v2l, v2g, wpack);
  conv_kernel<<<1024, 512, 0, stream>>>(wpack, xt, out);
}

// Round 14
// 50.386 us; speedup vs baseline: 1.1413x; 1.0435x over previous
//
#include <hip/hip_runtime.h>
#include <cstddef>
#include <cstdint>

typedef __attribute__((ext_vector_type(8))) short bf16x8;
typedef __attribute__((ext_vector_type(8))) unsigned short ushort8v;
typedef __attribute__((ext_vector_type(16))) float f32x16;

__device__ __forceinline__ unsigned short f2bf(float f) {
  union { float f; unsigned u; } v; v.f = f;
  unsigned r = v.u + 0x7FFFu + ((v.u >> 16) & 1u);  // round-to-nearest-even
  return (unsigned short)(r >> 16);
}

// ---------------- stage 1: global average pool (no transpose, no xt) ----
// grid = 4096 blocks (one (b,ch) plane each), 256 threads.
__global__ __launch_bounds__(256) void gap_kernel(const float* __restrict__ x,
                                                  float* __restrict__ gap) {
  const int bid = blockIdx.x;
  const float* p = x + (size_t)bid * 4096;
  const int t = threadIdx.x;
  float s = 0.f;
#pragma unroll
  for (int j = 0; j < 4; ++j) {
    const float4 v = *reinterpret_cast<const float4*>(p + j * 1024 + t * 4);
    s += v.x + v.y + v.z + v.w;
  }
#pragma unroll
  for (int off = 32; off > 0; off >>= 1) s += __shfl_down(s, off, 64);
  __shared__ float ws[4];
  if ((t & 63) == 0) ws[t >> 6] = s;
  __syncthreads();
  if (t == 0) gap[bid] = (ws[0] + ws[1] + ws[2] + ws[3]) * (1.f / 4096.f);
}

// ---------------- stage 2: glgf generation, gate FOLDED into weights ----
// grid = 128 blocks, 256 threads. wpack[bg] holds (w * c) in A-frag order.
__global__ __launch_bounds__(256) void glgf_pack(
    const float* __restrict__ gap,
    const float* __restrict__ w1l, const float* __restrict__ w1g1,
    const float* __restrict__ w1g2, const float* __restrict__ w2l,
    const float* __restrict__ w2g,
    const float* __restrict__ v1l, const float* __restrict__ v1g1,
    const float* __restrict__ v1g2, const float* __restrict__ v2l,
    const float* __restrict__ v2g,
    unsigned short* __restrict__ wpack) {
  __shared__ float gapL[256];
  __shared__ float t1L[16];
  __shared__ float h1L[256];
  __shared__ float red[256];
  __shared__ float cLs[32];
  const int bid = blockIdx.x;
  const int bg = ((bid & 7) << 4) | (bid >> 3);  // block on XCD bg>>4
  const int g = bg & 7, b = bg >> 3;
  const int c = threadIdx.x;
  gapL[c] = gap[b * 256 + c];
  __syncthreads();

  const int gbase = c & ~15;
  // ---- generator 1 ----
  float local1 = 0.f;
#pragma unroll
  for (int i = 0; i < 16; ++i) local1 += gapL[gbase + i] * w1l[c * 16 + i];
  if (c < 16) {
    float t = 0.f;
#pragma unroll
    for (int i = 0; i < 16; ++i) t += gapL[c * 16 + i] * w1g1[c * 16 + i];
    t1L[c] = t;
  }
  __syncthreads();
  float glob1 = 0.f;
#pragma unroll
  for (int gg = 0; gg < 16; ++gg) glob1 += t1L[gg] * w1g2[c * 16 + gg];
  const float h1 = 1.f / (1.f + expf(-(local1 + glob1)));
  h1L[c] = h1;
  red[c] = h1 * w2g[c];
  __syncthreads();
  for (int s = 128; s > 0; s >>= 1) {
    if (c < s) red[c] += red[c + s];
    __syncthreads();
  }
  const float glob2 = red[0];

  // ---- generator 2 (gate), folded into pack ----
  float local2 = 0.f;
#pragma unroll
  for (int i = 0; i < 16; ++i) local2 += gapL[gbase + i] * v1l[c * 16 + i];
  if (c < 16) {
    float t = 0.f;
#pragma unroll
    for (int i = 0; i < 16; ++i) t += gapL[c * 16 + i] * v1g1[c * 16 + i];
    t1L[c] = t;
  }
  __syncthreads();  // also separates red[0] reads from red reuse
  float glob1b = 0.f;
#pragma unroll
  for (int gg = 0; gg < 16; ++gg) glob1b += t1L[gg] * v1g2[c * 16 + gg];
  const float h2 = 1.f / (1.f + expf(-(local2 + glob1b)));
  red[c] = h2 * v2g[c];
  __syncthreads();
  for (int s = 128; s > 0; s >>= 1) {
    if (c < s) red[c] += red[c + s];
    __syncthreads();
  }
  if (c < 32) {
    const int o = g * 32 + c;
    float l = 0.f;
#pragma unroll
    for (int i = 0; i < 16; ++i) l += gapL[(o & ~15) + i] * v1l[o * 16 + i];
    float gl = 0.f;
#pragma unroll
    for (int gg = 0; gg < 16; ++gg) gl += t1L[gg] * v1g2[o * 16 + gg];
    const float h2o = 1.f / (1.f + expf(-(l + gl)));
    cLs[c] = h2o * v2l[o] + red[0];
  }
  __syncthreads();

  // ---- pack (w * c) for this (b,g): A-fragment order ----
  unsigned short* wpo = wpack + (size_t)bg * 9216;
#pragma unroll 4
  for (int it = 0; it < 36; ++it) {
    const int idx = it * 256 + c;
    const int kk = idx >> 9;
    const int rem = idx & 511;
    const int l = rem >> 3, e = rem & 7;
    const int oc = l & 31, hi = l >> 5;
    const int ic = ((kk & 1) << 4) + hi * 8 + e;
    const int sp = kk >> 1;
    const int o = (g << 5) + oc;
    const float wv = h1L[o] * w2l[o * 288 + ic * 9 + sp] + glob2;
    wpo[idx] = f2bf(wv * cLs[oc]);
  }
}

// ---------------- stage 3: fused transpose+conv, NO xt intermediate ----
// grid = 1024 blocks ((b,g) x 8-row strip), 512 threads = 8 waves, 2 blk/CU.
// Staging: per task a wave does 8 channel-strided coalesced fp32 reads of x
// (L3-hot), converts to bf16 in-register, writes ONE swizzled ds_write_b128
// per lane. Then ONE barrier, R13's MFMA loop, deferred stores.
__global__ __launch_bounds__(512, 4) void conv_kernel(
    const float* __restrict__ x, const unsigned short* __restrict__ wpack,
    float* __restrict__ out) {
  __shared__ __align__(16) unsigned short wpl[9216];    // 18432 B (A frags)
  __shared__ __align__(16) unsigned short btile[21120]; // 10r x 4cq x 66px x 16B

  const int bid = blockIdx.x;
  const int wkr = ((bid & 7) << 7) | (bid >> 3);  // XCD-chunked, bijective
  const int yq = wkr & 7;              // strip: output rows yq*8 .. +7
  const int bg = wkr >> 3;
  const int g = bg & 7, b = bg >> 3;
  const int tid = threadIdx.x;
  const int lane = tid & 63, wave = tid >> 6;   // 8 waves
  const int n = lane & 31, hi = lane >> 5;
  const int y0 = yq * 8;

  // ---- wpl copy: wpack (L2-hot) -> regs -> LDS ----
  {
    const uint4* src = reinterpret_cast<const uint4*>(wpack + (size_t)bg * 9216);
    uint4* dst = reinterpret_cast<uint4*>(wpl);
#pragma unroll
    for (int i = 0; i < 3; ++i) {
      const int li = i * 512 + tid;
      if (li < 1152) dst[li] = src[li];
    }
  }

  // ---- staging: 40 tasks (10 tile rows x 4 ic-quads), 5 per wave ----
  // tile row r = image row y0-1+r; lane n64 covers image px n64 -> tile px n64+1
  const float* xg = x + (size_t)(b * 256 + g * 32) * 4096;
#pragma unroll
  for (int i = 0; i < 5; ++i) {
    const int t = wave * 5 + i;
    const int r = t >> 2, icq = t & 3;
    const int y = y0 - 1 + r;
    const bool ok = (y >= 0) && (y < 64);
    ushort8v cell;
#pragma unroll
    for (int j = 0; j < 8; ++j) {
      const float v = ok ? xg[(size_t)(icq * 8 + j) * 4096 + y * 64 + lane] : 0.f;
      cell[j] = f2bf(v);
    }
    const int px = lane + 1;  // tile px (swizzle key = tile px, matches reader)
    *reinterpret_cast<ushort8v*>(
        &btile[((r * 4 + (icq ^ (px & 3))) * 66 + px) * 8]) = cell;
  }
  // halo columns (tile px 0 and 65): 10r x 4cq x 2 = 80 zero cells
  if (tid < 80) {
    const int r = tid >> 3, c8 = tid & 7;
    const int cq = c8 & 3, px = (c8 >> 2) ? 65 : 0;
    const ushort8v z = {0, 0, 0, 0, 0, 0, 0, 0};
    *reinterpret_cast<ushort8v*>(&btile[((r * 4 + cq) * 66 + px) * 8]) = z;
  }
  __syncthreads();

  // ---- 36 MFMA per wave: row y0+wave, both px halves (R13-proven) ----
  f32x16 acc0, acc1;
#pragma unroll
  for (int i = 0; i < 16; ++i) { acc0[i] = 0.f; acc1[i] = 0.f; }

  __builtin_amdgcn_s_setprio(1);
#pragma unroll
  for (int kk = 0; kk < 18; ++kk) {
    const int sp = kk >> 1;
    const int ky = sp / 3, kx = sp % 3;
    const int cq = ((kk & 1) << 1) + hi;
    const int pxA = n + kx;
    const int pxB = 32 + n + kx;
    const bf16x8 af =
        *reinterpret_cast<const bf16x8*>(&wpl[kk * 512 + lane * 8]);
    const bf16x8 bf0 = *reinterpret_cast<const bf16x8*>(
        &btile[((((wave + ky) << 2) + (cq ^ (pxA & 3))) * 66 + pxA) * 8]);
    const bf16x8 bf1 = *reinterpret_cast<const bf16x8*>(
        &btile[((((wave + ky) << 2) + (cq ^ (pxB & 3))) * 66 + pxB) * 8]);
    acc0 = __builtin_amdgcn_mfma_f32_32x32x16_bf16(af, bf0, acc0, 0, 0, 0);
    acc1 = __builtin_amdgcn_mfma_f32_32x32x16_bf16(af, bf1, acc1, 0, 0, 0);
  }
  __builtin_amdgcn_s_setprio(0);

  // ---- epilogue: deferred fire-and-forget stores (gate folded in wpack) ----
  const int y = y0 + wave;
  float* ob = out + (size_t)(b * 256 + g * 32) * 4096 + y * 64 + n +
              (size_t)(hi << 2) * 4096;
#pragma unroll
  for (int r = 0; r < 16; ++r) {
    const int row = (r & 3) + ((r >> 2) << 3);  // hi-term folded into ob
    ob[(size_t)row * 4096] = acc0[r];
    ob[(size_t)row * 4096 + 32] = acc1[r];
  }
}

extern "C" void kernel_launch(void* const* d_in, const int* in_sizes, int n_in,
                              void* d_out, int out_size, void* d_ws,
                              size_t ws_size, hipStream_t stream) {
  const float* x    = (const float*)d_in[0];
  const float* w1l  = (const float*)d_in[1];
  const float* w1g1 = (const float*)d_in[2];
  const float* w1g2 = (const float*)d_in[3];
  const float* w2l  = (const float*)d_in[4];
  const float* w2g  = (const float*)d_in[5];
  const float* v1l  = (const float*)d_in[6];
  const float* v1g1 = (const float*)d_in[7];
  const float* v1g2 = (const float*)d_in[8];
  const float* v2l  = (const float*)d_in[9];
  const float* v2g  = (const float*)d_in[10];
  float* out = (float*)d_out;

  float* gap = (float*)d_ws;                       // 4,096 f32
  unsigned short* wpack = (unsigned short*)(gap + 4096);  // 1,179,648 bf16

  gap_kernel<<<4096, 256, 0, stream>>>(x, gap);
  glgf_pack<<<128, 256, 0, stream>>>(gap, w1l, w1g1, w1g2, w2l, w2g,
                                     v1l, v1g1, v1g2, v2l, v2g, wpack);
  conv_kernel<<<1024, 512, 0, stream>>>(x, wpack, out);
}